// Round 1
// baseline (1141.840 us; speedup 1.0000x reference)
//
#include <hip/hip_runtime.h>
#include <math.h>

typedef __bf16 bf16;
typedef bf16 bf16x8 __attribute__((ext_vector_type(8)));
typedef bf16 bf16x4v __attribute__((ext_vector_type(4)));
typedef float f32x4 __attribute__((ext_vector_type(4)));

// Problem constants (B=4, S=2048, D=2048, H=16, dh=128)
#define BB 4
#define SS 2048
#define DD 2048
#define HH 16
#define DH 128

__device__ __forceinline__ void gload_lds16(const bf16* g, bf16* l) {
  __builtin_amdgcn_global_load_lds(
      (const __attribute__((address_space(1))) void*)g,
      (__attribute__((address_space(3))) void*)l, 16, 0, 0);
}

// ---------------------------------------------------------------- cast f32->bf16
__global__ __launch_bounds__(256) void cast_kernel(const float* __restrict__ in,
                                                   bf16* __restrict__ out, int n4) {
  int i = blockIdx.x * blockDim.x + threadIdx.x;
  if (i < n4) {
    const float4 v = ((const float4*)in)[i];
    bf16x4v o = {(bf16)v.x, (bf16)v.y, (bf16)v.z, (bf16)v.w};
    ((bf16x4v*)out)[i] = o;
  }
}

// ---------------------------------------------------------------- GEMM  C[m,n] = sum_k A[m,k]*W[n,k]
// MODE 0: bf16 out scattered to (b,h,s,d)   [Q, K before RoPE]
// MODE 1: bf16 out scattered to (b,h,d,s)   [V transposed]
// MODE 2: fp32 out row-major (m,n)          [final projection]
template <int MODE>
__global__ __launch_bounds__(256) void gemm_bt(const bf16* __restrict__ A,
                                               const bf16* __restrict__ Bw,
                                               bf16* __restrict__ Cb,
                                               float* __restrict__ Cf,
                                               int M, int N, int K) {
  __shared__ alignas(16) bf16 lA[128 * 64];
  __shared__ alignas(16) bf16 lB[128 * 64];
  const int tid = threadIdx.x;
  const int wave = tid >> 6, lane = tid & 63;
  const int quad = lane >> 4, l15 = lane & 15;
  const int m0 = blockIdx.y * 128, n0 = blockIdx.x * 128;
  const int wm = (wave >> 1) * 64, wn = (wave & 1) * 64;

  f32x4 acc[4][4] = {};

  for (int k0 = 0; k0 < K; k0 += 64) {
    __syncthreads();
#pragma unroll
    for (int i = 0; i < 4; ++i) {
      const int p = (wave * 4 + i) * 64 + lane;  // 16B chunk id, 0..1023
      const int r = p >> 3, c = p & 7;           // tile row / chunk-in-row
      gload_lds16(A + (size_t)(m0 + r) * K + k0 + c * 8, lA + (size_t)(wave * 4 + i) * 512);
      gload_lds16(Bw + (size_t)(n0 + r) * K + k0 + c * 8, lB + (size_t)(wave * 4 + i) * 512);
    }
    __syncthreads();
#pragma unroll
    for (int kk = 0; kk < 2; ++kk) {
      bf16x8 af[4], bfr[4];
#pragma unroll
      for (int t = 0; t < 4; ++t)
        af[t] = *(const bf16x8*)(lA + (wm + t * 16 + l15) * 64 + kk * 32 + quad * 8);
#pragma unroll
      for (int t = 0; t < 4; ++t)
        bfr[t] = *(const bf16x8*)(lB + (wn + t * 16 + l15) * 64 + kk * 32 + quad * 8);
#pragma unroll
      for (int mt = 0; mt < 4; ++mt)
#pragma unroll
        for (int nt = 0; nt < 4; ++nt)
          acc[mt][nt] = __builtin_amdgcn_mfma_f32_16x16x32_bf16(af[mt], bfr[nt], acc[mt][nt], 0, 0, 0);
    }
  }

#pragma unroll
  for (int mt = 0; mt < 4; ++mt) {
#pragma unroll
    for (int nt = 0; nt < 4; ++nt) {
#pragma unroll
      for (int r = 0; r < 4; ++r) {
        const int row = m0 + wm + mt * 16 + quad * 4 + r;  // C/D layout: row=quad*4+reg
        const int col = n0 + wn + nt * 16 + l15;           //             col=lane&15
        const float v = acc[mt][nt][r];
        if (MODE == 0) {
          const int b = row >> 11, s = row & (SS - 1);
          const int h = col >> 7, d = col & (DH - 1);
          Cb[((((size_t)b * HH + h) * SS + s) << 7) + d] = (bf16)v;
        } else if (MODE == 1) {
          const int b = row >> 11, s = row & (SS - 1);
          const int h = col >> 7, d = col & (DH - 1);
          Cb[(((size_t)b * HH + h) * DH + d) * SS + s] = (bf16)v;
        } else {
          Cf[(size_t)row * N + col] = v;
        }
      }
    }
  }
}

// ---------------------------------------------------------------- RoPE in-place on Q,K (b,h,s,d) bf16
__global__ __launch_bounds__(256) void rope_kernel(bf16* __restrict__ Q, bf16* __restrict__ Kb,
                                                   const int* __restrict__ pos, int total) {
  int idx = blockIdx.x * blockDim.x + threadIdx.x;
  if (idx >= total) return;            // total = B*H*S*64
  const int i = idx & 63;              // pair index
  const int s = (idx >> 6) & (SS - 1);
  const int bh = idx >> 17;            // S*64 = 2^17
  const size_t base = (((size_t)bh * SS + s) << 7) + 2 * i;
  const float p = (float)pos[s];
  const float inv_freq = exp2f((float)i * (-2.0f / 128.0f) * 13.28771238f);  // log2(10000)
  const float ang = p * inv_freq;
  float sv, cv;
  sincosf(ang, &sv, &cv);
  {
    float x1 = (float)Q[base], x2 = (float)Q[base + 1];
    Q[base] = (bf16)(x1 * cv - x2 * sv);
    Q[base + 1] = (bf16)(x1 * sv + x2 * cv);
  }
  {
    float x1 = (float)Kb[base], x2 = (float)Kb[base + 1];
    Kb[base] = (bf16)(x1 * cv - x2 * sv);
    Kb[base + 1] = (bf16)(x1 * sv + x2 * cv);
  }
}

// ---------------------------------------------------------------- flash attention (causal)
// Q,K: (B,H,S,128) bf16 ; Vt: (B,H,128,S) bf16 ; O: (B,S,H*128) bf16
__global__ __launch_bounds__(256) void flash_attn(const bf16* __restrict__ Q,
                                                  const bf16* __restrict__ Kg,
                                                  const bf16* __restrict__ Vt,
                                                  bf16* __restrict__ O) {
  __shared__ alignas(16) bf16 lK[64 * 136];   // 64 keys x 128 d, stride 136 (pad: bank stride 4)
  __shared__ alignas(16) bf16 lV[128 * 72];   // 128 d x 64 keys, stride 72
  __shared__ alignas(16) bf16 lP[4][16 * 72]; // per-wave P transpose scratch

  const int tid = threadIdx.x;
  const int wave = tid >> 6, lane = tid & 63;
  const int quad = lane >> 4, l15 = lane & 15;
  const int bh = blockIdx.y;
  const int q0 = blockIdx.x * 64;
  const bf16* Qh = Q + (size_t)bh * SS * DH;
  const bf16* Kh = Kg + (size_t)bh * SS * DH;
  const bf16* Vh = Vt + (size_t)bh * DH * SS;

  const int qr0 = q0 + wave * 16;  // this wave's 16 query rows
  bf16x8 aq[4];
#pragma unroll
  for (int t = 0; t < 4; ++t)
    aq[t] = *(const bf16x8*)(Qh + (size_t)(qr0 + l15) * DH + t * 32 + quad * 8);

  float mrow[4], lrow[4];
#pragma unroll
  for (int r = 0; r < 4; ++r) { mrow[r] = -1e30f; lrow[r] = 0.f; }
  f32x4 oacc[8] = {};

  const float scale = 0.08838834764831845f;  // 1/sqrt(128)
  const int nkb = (q0 >> 6) + 1;             // causal: keys 0 .. q0+63

  for (int kb = 0; kb < nkb; ++kb) {
    __syncthreads();
    // stage K tile (64x128, contiguous in global) and V^T tile (128x64, rows strided by S)
#pragma unroll
    for (int i = 0; i < 4; ++i) {
      const int p = tid + 256 * i;  // chunk id 0..1023
      const int rk = p >> 4, ck = p & 15;
      bf16x8 kv = *(const bf16x8*)(Kh + (size_t)(kb * 64) * DH + (size_t)p * 8);
      *(bf16x8*)(lK + rk * 136 + ck * 8) = kv;
      const int rv = p >> 3, cv = p & 7;
      bf16x8 vv = *(const bf16x8*)(Vh + (size_t)rv * SS + kb * 64 + cv * 8);
      *(bf16x8*)(lV + rv * 72 + cv * 8) = vv;
    }
    __syncthreads();

    // scores: S[q,key] for 16 q-rows x 64 keys
    float sm[4][4];
#pragma unroll
    for (int nt = 0; nt < 4; ++nt) {
      f32x4 sc = {};
#pragma unroll
      for (int t = 0; t < 4; ++t) {
        bf16x8 bk = *(const bf16x8*)(lK + (nt * 16 + l15) * 136 + t * 32 + quad * 8);
        sc = __builtin_amdgcn_mfma_f32_16x16x32_bf16(aq[t], bk, sc, 0, 0, 0);
      }
      const int key = kb * 64 + nt * 16 + l15;
#pragma unroll
      for (int r = 0; r < 4; ++r) {
        const int qrow = qr0 + quad * 4 + r;
        float v = sc[r] * scale;
        sm[nt][r] = (key <= qrow) ? v : -1e30f;
      }
    }

    // online softmax per row (rows quad*4+r live across the 16 lanes of this quad)
    float alpha[4];
#pragma unroll
    for (int r = 0; r < 4; ++r) {
      float mx = fmaxf(fmaxf(sm[0][r], sm[1][r]), fmaxf(sm[2][r], sm[3][r]));
#pragma unroll
      for (int off = 8; off >= 1; off >>= 1) mx = fmaxf(mx, __shfl_xor(mx, off, 16));
      const float mnew = fmaxf(mrow[r], mx);
      alpha[r] = __expf(mrow[r] - mnew);
      float rs = 0.f;
#pragma unroll
      for (int nt = 0; nt < 4; ++nt) {
        const float pv = __expf(sm[nt][r] - mnew);
        sm[nt][r] = pv;
        rs += pv;
      }
#pragma unroll
      for (int off = 8; off >= 1; off >>= 1) rs += __shfl_xor(rs, off, 16);
      lrow[r] = lrow[r] * alpha[r] + rs;
      mrow[r] = mnew;
    }

    // P: C-layout -> A-layout via per-wave LDS scratch
    bf16* lPw = lP[wave];
#pragma unroll
    for (int nt = 0; nt < 4; ++nt)
#pragma unroll
      for (int r = 0; r < 4; ++r)
        lPw[(quad * 4 + r) * 72 + nt * 16 + l15] = (bf16)sm[nt][r];
    __syncthreads();

    // rescale accumulator
#pragma unroll
    for (int n = 0; n < 8; ++n)
#pragma unroll
      for (int r = 0; r < 4; ++r) oacc[n][r] *= alpha[r];

    // PV: O[q,d] += P[q,key] * V[key,d]
#pragma unroll
    for (int kk = 0; kk < 2; ++kk) {
      bf16x8 ap = *(const bf16x8*)(lPw + l15 * 72 + kk * 32 + quad * 8);
#pragma unroll
      for (int n = 0; n < 8; ++n) {
        bf16x8 bv = *(const bf16x8*)(lV + (n * 16 + l15) * 72 + kk * 32 + quad * 8);
        oacc[n] = __builtin_amdgcn_mfma_f32_16x16x32_bf16(ap, bv, oacc[n], 0, 0, 0);
      }
    }
  }

  // epilogue: O[b, q, h*128 + d] = oacc / l
  const int b = bh >> 4, h = bh & 15;
#pragma unroll
  for (int r = 0; r < 4; ++r) {
    const int qrow = qr0 + quad * 4 + r;
    const float inv_l = 1.0f / lrow[r];
    bf16* orow = O + ((size_t)b * SS + qrow) * DD + h * DH;
#pragma unroll
    for (int n = 0; n < 8; ++n) orow[n * 16 + l15] = (bf16)(oacc[n][r] * inv_l);
  }
}

// ---------------------------------------------------------------- launch
extern "C" void kernel_launch(void* const* d_in, const int* in_sizes, int n_in,
                              void* d_out, int out_size, void* d_ws, size_t ws_size,
                              hipStream_t stream) {
  (void)in_sizes; (void)n_in; (void)out_size; (void)ws_size;
  const float* x = (const float*)d_in[0];
  const int* pos = (const int*)d_in[1];
  const float* wq = (const float*)d_in[2];
  const float* wk = (const float*)d_in[3];
  const float* wv = (const float*)d_in[4];
  const float* wo = (const float*)d_in[5];
  float* out = (float*)d_out;

  // workspace carve (bf16): total 100,663,296 el = 192 MiB
  bf16* xb  = (bf16*)d_ws;                 // B*S*D
  bf16* wqb = xb + (size_t)BB * SS * DD;   // D*D each
  bf16* wkb = wqb + (size_t)DD * DD;
  bf16* wvb = wkb + (size_t)DD * DD;
  bf16* wob = wvb + (size_t)DD * DD;
  bf16* Qb  = wob + (size_t)DD * DD;       // (B,H,S,128)
  bf16* Kbf = Qb + (size_t)BB * SS * DD;
  bf16* Vtb = Kbf + (size_t)BB * SS * DD;  // (B,H,128,S)
  bf16* Ob  = Vtb + (size_t)BB * SS * DD;  // (B,S,2048)

  const int nx = BB * SS * DD;
  const int nw = DD * DD;
  cast_kernel<<<nx / 4 / 256, 256, 0, stream>>>(x, xb, nx / 4);
  cast_kernel<<<nw / 4 / 256, 256, 0, stream>>>(wq, wqb, nw / 4);
  cast_kernel<<<nw / 4 / 256, 256, 0, stream>>>(wk, wkb, nw / 4);
  cast_kernel<<<nw / 4 / 256, 256, 0, stream>>>(wv, wvb, nw / 4);
  cast_kernel<<<nw / 4 / 256, 256, 0, stream>>>(wo, wob, nw / 4);

  dim3 gg(DD / 128, (BB * SS) / 128);  // (16, 64)
  gemm_bt<0><<<gg, 256, 0, stream>>>(xb, wqb, Qb, nullptr, BB * SS, DD, DD);
  gemm_bt<0><<<gg, 256, 0, stream>>>(xb, wkb, Kbf, nullptr, BB * SS, DD, DD);
  gemm_bt<1><<<gg, 256, 0, stream>>>(xb, wvb, Vtb, nullptr, BB * SS, DD, DD);

  const int nrope = BB * HH * SS * 64;
  rope_kernel<<<nrope / 256, 256, 0, stream>>>(Qb, Kbf, pos, nrope);

  flash_attn<<<dim3(SS / 64, BB * HH), 256, 0, stream>>>(Qb, Kbf, Vtb, Ob);

  gemm_bt<2><<<gg, 256, 0, stream>>>(Ob, wob, nullptr, out, BB * SS, DD, DD);
}

// Round 2
// 1006.825 us; speedup vs baseline: 1.1341x; 1.1341x over previous
//
#include <hip/hip_runtime.h>
#include <math.h>

typedef __bf16 bf16;
typedef bf16 bf16x8 __attribute__((ext_vector_type(8)));
typedef bf16 bf16x4v __attribute__((ext_vector_type(4)));
typedef float f32x4 __attribute__((ext_vector_type(4)));

// Problem constants (B=4, S=2048, D=2048, H=16, dh=128)
#define BB 4
#define SS 2048
#define DD 2048
#define HH 16
#define DH 128

__device__ __forceinline__ void gload_lds16(const bf16* g, bf16* l) {
  __builtin_amdgcn_global_load_lds(
      (const __attribute__((address_space(1))) void*)g,
      (__attribute__((address_space(3))) void*)l, 16, 0, 0);
}

// ---------------------------------------------------------------- cast f32->bf16
__global__ __launch_bounds__(256) void cast_kernel(const float* __restrict__ in,
                                                   bf16* __restrict__ out, int n4) {
  int i = blockIdx.x * blockDim.x + threadIdx.x;
  if (i < n4) {
    const float4 v = ((const float4*)in)[i];
    bf16x4v o = {(bf16)v.x, (bf16)v.y, (bf16)v.z, (bf16)v.w};
    ((bf16x4v*)out)[i] = o;
  }
}

// ---------------------------------------------------------------- GEMM  C[m,n] = sum_k A[m,k]*W[n,k]
// MODE 0: bf16 out scattered to (b,h,s,d)   [Q, K before RoPE]
// MODE 1: bf16 out scattered to (b,h,d,s)   [V transposed]
// MODE 2: fp32 out row-major (m,n)          [final projection]
template <int MODE>
__global__ __launch_bounds__(256) void gemm_bt(const bf16* __restrict__ A,
                                               const bf16* __restrict__ Bw,
                                               bf16* __restrict__ Cb,
                                               float* __restrict__ Cf,
                                               int M, int N, int K) {
  __shared__ alignas(16) bf16 lA[128 * 64];
  __shared__ alignas(16) bf16 lB[128 * 64];
  const int tid = threadIdx.x;
  const int wave = tid >> 6, lane = tid & 63;
  const int quad = lane >> 4, l15 = lane & 15;
  const int m0 = blockIdx.y * 128, n0 = blockIdx.x * 128;
  const int wm = (wave >> 1) * 64, wn = (wave & 1) * 64;

  f32x4 acc[4][4] = {};

  for (int k0 = 0; k0 < K; k0 += 64) {
    __syncthreads();
#pragma unroll
    for (int i = 0; i < 4; ++i) {
      const int p = (wave * 4 + i) * 64 + lane;  // 16B chunk id, 0..1023
      const int r = p >> 3, c = p & 7;           // tile row / chunk-in-row
      gload_lds16(A + (size_t)(m0 + r) * K + k0 + c * 8, lA + (size_t)(wave * 4 + i) * 512);
      gload_lds16(Bw + (size_t)(n0 + r) * K + k0 + c * 8, lB + (size_t)(wave * 4 + i) * 512);
    }
    __syncthreads();
#pragma unroll
    for (int kk = 0; kk < 2; ++kk) {
      bf16x8 af[4], bfr[4];
#pragma unroll
      for (int t = 0; t < 4; ++t)
        af[t] = *(const bf16x8*)(lA + (wm + t * 16 + l15) * 64 + kk * 32 + quad * 8);
#pragma unroll
      for (int t = 0; t < 4; ++t)
        bfr[t] = *(const bf16x8*)(lB + (wn + t * 16 + l15) * 64 + kk * 32 + quad * 8);
#pragma unroll
      for (int mt = 0; mt < 4; ++mt)
#pragma unroll
        for (int nt = 0; nt < 4; ++nt)
          acc[mt][nt] = __builtin_amdgcn_mfma_f32_16x16x32_bf16(af[mt], bfr[nt], acc[mt][nt], 0, 0, 0);
    }
  }

#pragma unroll
  for (int mt = 0; mt < 4; ++mt) {
#pragma unroll
    for (int nt = 0; nt < 4; ++nt) {
#pragma unroll
      for (int r = 0; r < 4; ++r) {
        const int row = m0 + wm + mt * 16 + quad * 4 + r;  // C/D layout: row=quad*4+reg
        const int col = n0 + wn + nt * 16 + l15;           //             col=lane&15
        const float v = acc[mt][nt][r];
        if (MODE == 0) {
          const int b = row >> 11, s = row & (SS - 1);
          const int h = col >> 7, d = col & (DH - 1);
          Cb[((((size_t)b * HH + h) * SS + s) << 7) + d] = (bf16)v;
        } else if (MODE == 1) {
          const int b = row >> 11, s = row & (SS - 1);
          const int h = col >> 7, d = col & (DH - 1);
          Cb[(((size_t)b * HH + h) * DH + d) * SS + s] = (bf16)v;
        } else {
          Cf[(size_t)row * N + col] = v;
        }
      }
    }
  }
}

// ---------------------------------------------------------------- RoPE in-place on Q,K (b,h,s,d) bf16
__global__ __launch_bounds__(256) void rope_kernel(bf16* __restrict__ Q, bf16* __restrict__ Kb,
                                                   const int* __restrict__ pos, int total) {
  int idx = blockIdx.x * blockDim.x + threadIdx.x;
  if (idx >= total) return;            // total = B*H*S*64
  const int i = idx & 63;              // pair index
  const int s = (idx >> 6) & (SS - 1);
  const int bh = idx >> 17;            // S*64 = 2^17
  const size_t base = (((size_t)bh * SS + s) << 7) + 2 * i;
  const float p = (float)pos[s];
  const float inv_freq = exp2f((float)i * (-2.0f / 128.0f) * 13.28771238f);  // log2(10000)
  const float ang = p * inv_freq;
  float sv, cv;
  sincosf(ang, &sv, &cv);
  {
    float x1 = (float)Q[base], x2 = (float)Q[base + 1];
    Q[base] = (bf16)(x1 * cv - x2 * sv);
    Q[base + 1] = (bf16)(x1 * sv + x2 * cv);
  }
  {
    float x1 = (float)Kb[base], x2 = (float)Kb[base + 1];
    Kb[base] = (bf16)(x1 * cv - x2 * sv);
    Kb[base + 1] = (bf16)(x1 * sv + x2 * cv);
  }
}

// ---------------------------------------------------------------- flash attention (causal, transposed scores)
// Q,K: (B,H,S,128) bf16 ; Vt: (B,H,128,S) bf16 ; O: (B,S,H*128) bf16
// Block: 128 q-rows, 4 waves x 32 q each. Scores computed as S^T = K*Q^T so each
// lane's 16 score regs belong to ONE query (q = lane&15): softmax reduce is
// in-register + 2 shuffles instead of 32.
__global__ __launch_bounds__(256, 3) void flash_attn(const bf16* __restrict__ Q,
                                                     const bf16* __restrict__ Kg,
                                                     const bf16* __restrict__ Vt,
                                                     bf16* __restrict__ O) {
  __shared__ alignas(16) bf16 lK[64 * 136];    // 64 keys x 128 d (stride 136: 16B-aligned rows, 2-way banks)
  __shared__ alignas(16) bf16 lV[128 * 72];    // 128 d x 64 keys (stride 72)
  __shared__ alignas(16) bf16 lP[4][32 * 72];  // per-wave P^T->A-layout scratch (32 q x 64 keys)

  const int tid = threadIdx.x;
  const int wave = tid >> 6, lane = tid & 63;
  const int quad = lane >> 4, l15 = lane & 15;
  const int bh = blockIdx.y;
  const int q0 = (gridDim.x - 1 - blockIdx.x) * 128;  // heavy blocks first (causal balance)
  const bf16* Qh = Q + (size_t)bh * SS * DH;
  const bf16* Kh = Kg + (size_t)bh * SS * DH;
  const bf16* Vh = Vt + (size_t)bh * DH * SS;

  const int qw = q0 + wave * 32;  // this wave's 32 query rows
  // Q fragments (B-operand layout: n=q=l15, k=d=quad*8+j)
  bf16x8 qf[2][4];
#pragma unroll
  for (int qt = 0; qt < 2; ++qt)
#pragma unroll
    for (int t = 0; t < 4; ++t)
      qf[qt][t] = *(const bf16x8*)(Qh + (size_t)(qw + qt * 16 + l15) * DH + t * 32 + quad * 8);

  float m_[2] = {-1e30f, -1e30f}, l_[2] = {0.f, 0.f};
  f32x4 oacc[2][8] = {};
  const float scale = 0.08838834764831845f;  // 1/sqrt(128)
  const int nkb = (q0 >> 6) + 2;             // keys 0 .. q0+127
  bf16* lPw = lP[wave];

  for (int kb = 0; kb < nkb; ++kb) {
    __syncthreads();
    // stage K tile (64x128, contiguous) and V^T tile (128x64, rows strided by S)
#pragma unroll
    for (int i = 0; i < 4; ++i) {
      const int p = tid + 256 * i;  // chunk id 0..1023
      bf16x8 kv = *(const bf16x8*)(Kh + (size_t)(kb * 64) * DH + (size_t)p * 8);
      *(bf16x8*)(lK + (p >> 4) * 136 + (p & 15) * 8) = kv;
      bf16x8 vv = *(const bf16x8*)(Vh + (size_t)(p >> 3) * SS + kb * 64 + (p & 7) * 8);
      *(bf16x8*)(lV + (p >> 3) * 72 + (p & 7) * 8) = vv;
    }
    __syncthreads();

    // S^T[key, q]: A = K-frag (m=key), B = Q-frag (n=q)
    f32x4 sacc[2][4] = {};
#pragma unroll
    for (int nt = 0; nt < 4; ++nt) {
      bf16x8 kf[4];
#pragma unroll
      for (int t = 0; t < 4; ++t)
        kf[t] = *(const bf16x8*)(lK + (nt * 16 + l15) * 136 + t * 32 + quad * 8);
#pragma unroll
      for (int qt = 0; qt < 2; ++qt)
#pragma unroll
        for (int t = 0; t < 4; ++t)
          sacc[qt][nt] = __builtin_amdgcn_mfma_f32_16x16x32_bf16(kf[t], qf[qt][t], sacc[qt][nt], 0, 0, 0);
    }

#pragma unroll
    for (int qt = 0; qt < 2; ++qt) {
      const int qq = qw + qt * 16 + l15;  // this lane's query row
      float sv[16];
#pragma unroll
      for (int nt = 0; nt < 4; ++nt)
#pragma unroll
        for (int r = 0; r < 4; ++r) {
          const int key = kb * 64 + nt * 16 + quad * 4 + r;
          const float v = sacc[qt][nt][r] * scale;
          sv[nt * 4 + r] = (key <= qq) ? v : -1e30f;
        }
      float mx = sv[0];
#pragma unroll
      for (int i = 1; i < 16; ++i) mx = fmaxf(mx, sv[i]);
      mx = fmaxf(mx, __shfl_xor(mx, 16));
      mx = fmaxf(mx, __shfl_xor(mx, 32));
      const float mnew = fmaxf(m_[qt], mx);
      const float al = __expf(m_[qt] - mnew);
      float rs = 0.f;
#pragma unroll
      for (int i = 0; i < 16; ++i) {
        const float pv = __expf(sv[i] - mnew);
        sv[i] = pv;
        rs += pv;
      }
      rs += __shfl_xor(rs, 16);
      rs += __shfl_xor(rs, 32);
      l_[qt] = l_[qt] * al + rs;
      m_[qt] = mnew;

      // P^T -> A-layout: 4 consecutive keys per quad -> packed 8B writes
#pragma unroll
      for (int nt = 0; nt < 4; ++nt) {
        bf16x4v pk = {(bf16)sv[nt * 4 + 0], (bf16)sv[nt * 4 + 1], (bf16)sv[nt * 4 + 2], (bf16)sv[nt * 4 + 3]};
        *(bf16x4v*)(lPw + (qt * 16 + l15) * 72 + nt * 16 + quad * 4) = pk;
      }

      // per-output-row alpha (rows are quad*4+r in C layout) via bpermute
      float ar[4];
#pragma unroll
      for (int r = 0; r < 4; ++r) ar[r] = __shfl(al, quad * 4 + r, 16);
#pragma unroll
      for (int nd = 0; nd < 8; ++nd)
#pragma unroll
        for (int r = 0; r < 4; ++r) oacc[qt][nd][r] *= ar[r];
    }

    asm volatile("s_waitcnt lgkmcnt(0)" ::: "memory");  // P writes visible to own wave's reads

    // PV: O[q,d] += P[q,key] * V[key,d]
#pragma unroll
    for (int kk = 0; kk < 2; ++kk) {
      bf16x8 ap[2];
#pragma unroll
      for (int qt = 0; qt < 2; ++qt)
        ap[qt] = *(const bf16x8*)(lPw + (qt * 16 + l15) * 72 + kk * 32 + quad * 8);
#pragma unroll
      for (int nd = 0; nd < 8; ++nd) {
        bf16x8 bv = *(const bf16x8*)(lV + (nd * 16 + l15) * 72 + kk * 32 + quad * 8);
        oacc[0][nd] = __builtin_amdgcn_mfma_f32_16x16x32_bf16(ap[0], bv, oacc[0][nd], 0, 0, 0);
        oacc[1][nd] = __builtin_amdgcn_mfma_f32_16x16x32_bf16(ap[1], bv, oacc[1][nd], 0, 0, 0);
      }
    }
  }

  // epilogue: O[b, q, h*128 + d] = oacc / l
  const int b = bh >> 4, h = bh & 15;
#pragma unroll
  for (int qt = 0; qt < 2; ++qt) {
    float il[4];
#pragma unroll
    for (int r = 0; r < 4; ++r) il[r] = 1.0f / __shfl(l_[qt], quad * 4 + r, 16);
#pragma unroll
    for (int r = 0; r < 4; ++r) {
      const int qrow = qw + qt * 16 + quad * 4 + r;
      bf16* orow = O + ((size_t)b * SS + qrow) * DD + h * DH;
#pragma unroll
      for (int nd = 0; nd < 8; ++nd) orow[nd * 16 + l15] = (bf16)(oacc[qt][nd][r] * il[r]);
    }
  }
}

// ---------------------------------------------------------------- launch
extern "C" void kernel_launch(void* const* d_in, const int* in_sizes, int n_in,
                              void* d_out, int out_size, void* d_ws, size_t ws_size,
                              hipStream_t stream) {
  (void)in_sizes; (void)n_in; (void)out_size; (void)ws_size;
  const float* x = (const float*)d_in[0];
  const int* pos = (const int*)d_in[1];
  const float* wq = (const float*)d_in[2];
  const float* wk = (const float*)d_in[3];
  const float* wv = (const float*)d_in[4];
  const float* wo = (const float*)d_in[5];
  float* out = (float*)d_out;

  // workspace carve (bf16): total 100,663,296 el = 192 MiB
  bf16* xb  = (bf16*)d_ws;                 // B*S*D
  bf16* wqb = xb + (size_t)BB * SS * DD;   // D*D each
  bf16* wkb = wqb + (size_t)DD * DD;
  bf16* wvb = wkb + (size_t)DD * DD;
  bf16* wob = wvb + (size_t)DD * DD;
  bf16* Qb  = wob + (size_t)DD * DD;       // (B,H,S,128)
  bf16* Kbf = Qb + (size_t)BB * SS * DD;
  bf16* Vtb = Kbf + (size_t)BB * SS * DD;  // (B,H,128,S)
  bf16* Ob  = Vtb + (size_t)BB * SS * DD;  // (B,S,2048)

  const int nx = BB * SS * DD;
  const int nw = DD * DD;
  cast_kernel<<<nx / 4 / 256, 256, 0, stream>>>(x, xb, nx / 4);
  cast_kernel<<<nw / 4 / 256, 256, 0, stream>>>(wq, wqb, nw / 4);
  cast_kernel<<<nw / 4 / 256, 256, 0, stream>>>(wk, wkb, nw / 4);
  cast_kernel<<<nw / 4 / 256, 256, 0, stream>>>(wv, wvb, nw / 4);
  cast_kernel<<<nw / 4 / 256, 256, 0, stream>>>(wo, wob, nw / 4);

  dim3 gg(DD / 128, (BB * SS) / 128);  // (16, 64)
  gemm_bt<0><<<gg, 256, 0, stream>>>(xb, wqb, Qb, nullptr, BB * SS, DD, DD);
  gemm_bt<0><<<gg, 256, 0, stream>>>(xb, wkb, Kbf, nullptr, BB * SS, DD, DD);
  gemm_bt<1><<<gg, 256, 0, stream>>>(xb, wvb, Vtb, nullptr, BB * SS, DD, DD);

  const int nrope = BB * HH * SS * 64;
  rope_kernel<<<nrope / 256, 256, 0, stream>>>(Qb, Kbf, pos, nrope);

  flash_attn<<<dim3(SS / 128, BB * HH), 256, 0, stream>>>(Qb, Kbf, Vtb, Ob);

  gemm_bt<2><<<gg, 256, 0, stream>>>(Ob, wob, nullptr, out, BB * SS, DD, DD);
}

// Round 3
// 833.002 us; speedup vs baseline: 1.3708x; 1.2087x over previous
//
#include <hip/hip_runtime.h>
#include <math.h>

typedef __bf16 bf16;
typedef bf16 bf16x8 __attribute__((ext_vector_type(8)));
typedef bf16 bf16x4v __attribute__((ext_vector_type(4)));
typedef float f32x4 __attribute__((ext_vector_type(4)));

// Problem constants (B=4, S=2048, D=2048, H=16, dh=128)
#define BB 4
#define SS 2048
#define DD 2048
#define HH 16
#define DH 128

__device__ __forceinline__ void gload_lds16(const bf16* g, bf16* l) {
  __builtin_amdgcn_global_load_lds(
      (const __attribute__((address_space(1))) void*)g,
      (__attribute__((address_space(3))) void*)l, 16, 0, 0);
}

// ---------------------------------------------------------------- cast f32->bf16
__global__ __launch_bounds__(256) void cast_kernel(const float* __restrict__ in,
                                                   bf16* __restrict__ out, int n4) {
  int i = blockIdx.x * blockDim.x + threadIdx.x;
  if (i < n4) {
    const float4 v = ((const float4*)in)[i];
    bf16x4v o = {(bf16)v.x, (bf16)v.y, (bf16)v.z, (bf16)v.w};
    ((bf16x4v*)out)[i] = o;
  }
}

// ---------------------------------------------------------------- GEMM  C[m,n] = sum_k A[m,k]*W[n,k]
// MODE 0: bf16 out scattered to (b,h,s,d)   [Q, K before RoPE]
// MODE 1: bf16 out scattered to (b,h,d,s)   [V transposed]
// MODE 2: fp32 out row-major (m,n)          [final projection]
template <int MODE>
__global__ __launch_bounds__(256) void gemm_bt(const bf16* __restrict__ A,
                                               const bf16* __restrict__ Bw,
                                               bf16* __restrict__ Cb,
                                               float* __restrict__ Cf,
                                               int M, int N, int K) {
  __shared__ alignas(16) bf16 lA[128 * 64];
  __shared__ alignas(16) bf16 lB[128 * 64];
  const int tid = threadIdx.x;
  const int wave = tid >> 6, lane = tid & 63;
  const int quad = lane >> 4, l15 = lane & 15;
  const int m0 = blockIdx.y * 128, n0 = blockIdx.x * 128;
  const int wm = (wave >> 1) * 64, wn = (wave & 1) * 64;

  f32x4 acc[4][4] = {};

  for (int k0 = 0; k0 < K; k0 += 64) {
    __syncthreads();
#pragma unroll
    for (int i = 0; i < 4; ++i) {
      const int p = (wave * 4 + i) * 64 + lane;  // 16B chunk id, 0..1023
      const int r = p >> 3, c = p & 7;           // tile row / chunk-in-row
      gload_lds16(A + (size_t)(m0 + r) * K + k0 + c * 8, lA + (size_t)(wave * 4 + i) * 512);
      gload_lds16(Bw + (size_t)(n0 + r) * K + k0 + c * 8, lB + (size_t)(wave * 4 + i) * 512);
    }
    __syncthreads();
#pragma unroll
    for (int kk = 0; kk < 2; ++kk) {
      bf16x8 af[4], bfr[4];
#pragma unroll
      for (int t = 0; t < 4; ++t)
        af[t] = *(const bf16x8*)(lA + (wm + t * 16 + l15) * 64 + kk * 32 + quad * 8);
#pragma unroll
      for (int t = 0; t < 4; ++t)
        bfr[t] = *(const bf16x8*)(lB + (wn + t * 16 + l15) * 64 + kk * 32 + quad * 8);
#pragma unroll
      for (int mt = 0; mt < 4; ++mt)
#pragma unroll
        for (int nt = 0; nt < 4; ++nt)
          acc[mt][nt] = __builtin_amdgcn_mfma_f32_16x16x32_bf16(af[mt], bfr[nt], acc[mt][nt], 0, 0, 0);
    }
  }

#pragma unroll
  for (int mt = 0; mt < 4; ++mt) {
#pragma unroll
    for (int nt = 0; nt < 4; ++nt) {
#pragma unroll
      for (int r = 0; r < 4; ++r) {
        const int row = m0 + wm + mt * 16 + quad * 4 + r;  // C/D layout: row=quad*4+reg
        const int col = n0 + wn + nt * 16 + l15;           //             col=lane&15
        const float v = acc[mt][nt][r];
        if (MODE == 0) {
          const int b = row >> 11, s = row & (SS - 1);
          const int h = col >> 7, d = col & (DH - 1);
          Cb[((((size_t)b * HH + h) * SS + s) << 7) + d] = (bf16)v;
        } else if (MODE == 1) {
          const int b = row >> 11, s = row & (SS - 1);
          const int h = col >> 7, d = col & (DH - 1);
          Cb[(((size_t)b * HH + h) * DH + d) * SS + s] = (bf16)v;
        } else {
          Cf[(size_t)row * N + col] = v;
        }
      }
    }
  }
}

// ---------------------------------------------------------------- RoPE in-place on Q,K (b,h,s,d) bf16
__global__ __launch_bounds__(256) void rope_kernel(bf16* __restrict__ Q, bf16* __restrict__ Kb,
                                                   const int* __restrict__ pos, int total) {
  int idx = blockIdx.x * blockDim.x + threadIdx.x;
  if (idx >= total) return;            // total = B*H*S*64
  const int i = idx & 63;              // pair index
  const int s = (idx >> 6) & (SS - 1);
  const int bh = idx >> 17;            // S*64 = 2^17
  const size_t base = (((size_t)bh * SS + s) << 7) + 2 * i;
  const float p = (float)pos[s];
  const float inv_freq = exp2f((float)i * (-2.0f / 128.0f) * 13.28771238f);  // log2(10000)
  const float ang = p * inv_freq;
  float sv, cv;
  sincosf(ang, &sv, &cv);
  {
    float x1 = (float)Q[base], x2 = (float)Q[base + 1];
    Q[base] = (bf16)(x1 * cv - x2 * sv);
    Q[base + 1] = (bf16)(x1 * sv + x2 * cv);
  }
  {
    float x1 = (float)Kb[base], x2 = (float)Kb[base + 1];
    Kb[base] = (bf16)(x1 * cv - x2 * sv);
    Kb[base + 1] = (bf16)(x1 * sv + x2 * cv);
  }
}

// ---------------------------------------------------------------- flash attention (causal, transposed scores, reg-dbuf)
// Q,K: (B,H,S,128) bf16 ; Vt: (B,H,128,S) bf16 ; O: (B,S,H*128) bf16
// Block: 64 q-rows, 4 waves x 16 q. S^T = K*Q^T so each lane's 16 score regs
// belong to ONE query (q = lane&15). Softmax done IN PLACE in sacc (no copy).
// K/V staging is register-double-buffered: tile kb+1's global loads issue at
// the top of compute on tile kb, LDS write happens after the tail barrier.
__global__ __launch_bounds__(256, 3) void flash_attn(const bf16* __restrict__ Q,
                                                     const bf16* __restrict__ Kg,
                                                     const bf16* __restrict__ Vt,
                                                     bf16* __restrict__ O) {
  __shared__ alignas(16) bf16 lK[64 * 136];    // 64 keys x 128 d (pad: rows start on distinct even banks)
  __shared__ alignas(16) bf16 lV[128 * 72];    // 128 d x 64 keys
  __shared__ alignas(16) bf16 lP[4][16 * 72];  // per-wave P scratch (16 q x 64 keys, A-layout)

  const int tid = threadIdx.x;
  const int wave = tid >> 6, lane = tid & 63;
  const int quad = lane >> 4, l15 = lane & 15;
  const int bh = blockIdx.y;
  const int q0 = (gridDim.x - 1 - blockIdx.x) * 64;  // heavy blocks first
  const bf16* Qh = Q + (size_t)bh * SS * DH;
  const bf16* Kh = Kg + (size_t)bh * SS * DH;
  const bf16* Vh = Vt + (size_t)bh * DH * SS;

  const int qw = q0 + wave * 16;
  const int qq = qw + l15;  // this lane's query row
  // Q fragment (B-operand layout: n=q=l15, k=d=quad*8+j)
  bf16x8 qf[4];
#pragma unroll
  for (int t = 0; t < 4; ++t)
    qf[t] = *(const bf16x8*)(Qh + (size_t)qq * DH + t * 32 + quad * 8);

  float m_ = -1e30f, l_ = 0.f;
  f32x4 oacc[8] = {};
  // softmax in base-2 domain: scores pre-multiplied by scale*log2(e)
  const float cs = 0.08838834764831845f * 1.4426950408889634f;
  const int nkb = (q0 >> 6) + 1;  // keys 0 .. q0+63
  bf16* lPw = lP[wave];

  bf16x8 kreg[4], vreg[4];
  auto ld_tile = [&](int kb) {
#pragma unroll
    for (int i = 0; i < 4; ++i) {
      const int p = tid + 256 * i;  // 16B chunk id 0..1023
      kreg[i] = *(const bf16x8*)(Kh + (size_t)(kb * 64) * DH + (size_t)p * 8);
      vreg[i] = *(const bf16x8*)(Vh + (size_t)(p >> 3) * SS + kb * 64 + (p & 7) * 8);
    }
  };
  auto st_tile = [&]() {
#pragma unroll
    for (int i = 0; i < 4; ++i) {
      const int p = tid + 256 * i;
      *(bf16x8*)(lK + (p >> 4) * 136 + (p & 15) * 8) = kreg[i];
      *(bf16x8*)(lV + (p >> 3) * 72 + (p & 7) * 8) = vreg[i];
    }
  };

  ld_tile(0);
  st_tile();

  for (int kb = 0; kb < nkb; ++kb) {
    __syncthreads();  // tile kb visible to all
    if (kb + 1 < nkb) ld_tile(kb + 1);  // overlap next tile's latency with compute

    // S^T[key, q]: A = K-frag (m=key), B = Q-frag (n=q)
    f32x4 sacc[4] = {};
#pragma unroll
    for (int nt = 0; nt < 4; ++nt) {
#pragma unroll
      for (int t = 0; t < 4; ++t) {
        bf16x8 kf = *(const bf16x8*)(lK + (nt * 16 + l15) * 136 + t * 32 + quad * 8);
        sacc[nt] = __builtin_amdgcn_mfma_f32_16x16x32_bf16(kf, qf[t], sacc[nt], 0, 0, 0);
      }
    }

    // softmax (in place): each lane holds 16 scores of query qq, keys nt*16+quad*4+r
#pragma unroll
    for (int nt = 0; nt < 4; ++nt)
#pragma unroll
      for (int r = 0; r < 4; ++r) {
        const int key = kb * 64 + nt * 16 + quad * 4 + r;
        sacc[nt][r] = (key <= qq) ? sacc[nt][r] * cs : -1e30f;
      }
    float mx = sacc[0][0];
#pragma unroll
    for (int nt = 0; nt < 4; ++nt)
#pragma unroll
      for (int r = 0; r < 4; ++r) mx = fmaxf(mx, sacc[nt][r]);
    mx = fmaxf(mx, __shfl_xor(mx, 16));
    mx = fmaxf(mx, __shfl_xor(mx, 32));
    const float mnew = fmaxf(m_, mx);
    const float al = exp2f(m_ - mnew);
    float rs = 0.f;
#pragma unroll
    for (int nt = 0; nt < 4; ++nt)
#pragma unroll
      for (int r = 0; r < 4; ++r) {
        const float pv = exp2f(sacc[nt][r] - mnew);
        sacc[nt][r] = pv;
        rs += pv;
      }
    rs += __shfl_xor(rs, 16);
    rs += __shfl_xor(rs, 32);
    l_ = l_ * al + rs;
    m_ = mnew;

    // P -> A-layout scratch: 4 consecutive keys per quad, packed 8B writes
#pragma unroll
    for (int nt = 0; nt < 4; ++nt) {
      bf16x4v pk = {(bf16)sacc[nt][0], (bf16)sacc[nt][1], (bf16)sacc[nt][2], (bf16)sacc[nt][3]};
      *(bf16x4v*)(lPw + l15 * 72 + nt * 16 + quad * 4) = pk;
    }

    // rescale accumulator: alpha for C-layout rows q=quad*4+r lives at lane q
    float ar[4];
#pragma unroll
    for (int r = 0; r < 4; ++r) ar[r] = __shfl(al, quad * 4 + r, 16);
#pragma unroll
    for (int nd = 0; nd < 8; ++nd)
#pragma unroll
      for (int r = 0; r < 4; ++r) oacc[nd][r] *= ar[r];

    // PV: O[q,d] += P[q,key] * V[key,d]
#pragma unroll
    for (int kk = 0; kk < 2; ++kk) {
      bf16x8 ap = *(const bf16x8*)(lPw + l15 * 72 + kk * 32 + quad * 8);
#pragma unroll
      for (int nd = 0; nd < 8; ++nd) {
        bf16x8 bv = *(const bf16x8*)(lV + (nd * 16 + l15) * 72 + kk * 32 + quad * 8);
        oacc[nd] = __builtin_amdgcn_mfma_f32_16x16x32_bf16(ap, bv, oacc[nd], 0, 0, 0);
      }
    }

    __syncthreads();  // everyone done reading tile kb
    if (kb + 1 < nkb) st_tile();  // commit prefetched tile kb+1 to LDS
  }

  // epilogue: O[b, q, h*128 + d] = oacc / l   (C rows q=quad*4+r, l_ lives at lane q)
  const int b = bh >> 4, h = bh & 15;
  float il[4];
#pragma unroll
  for (int r = 0; r < 4; ++r) il[r] = 1.0f / __shfl(l_, quad * 4 + r, 16);
#pragma unroll
  for (int r = 0; r < 4; ++r) {
    const int qrow = qw + quad * 4 + r;
    bf16* orow = O + ((size_t)b * SS + qrow) * DD + h * DH;
#pragma unroll
    for (int nd = 0; nd < 8; ++nd) orow[nd * 16 + l15] = (bf16)(oacc[nd][r] * il[r]);
  }
}

// ---------------------------------------------------------------- launch
extern "C" void kernel_launch(void* const* d_in, const int* in_sizes, int n_in,
                              void* d_out, int out_size, void* d_ws, size_t ws_size,
                              hipStream_t stream) {
  (void)in_sizes; (void)n_in; (void)out_size; (void)ws_size;
  const float* x = (const float*)d_in[0];
  const int* pos = (const int*)d_in[1];
  const float* wq = (const float*)d_in[2];
  const float* wk = (const float*)d_in[3];
  const float* wv = (const float*)d_in[4];
  const float* wo = (const float*)d_in[5];
  float* out = (float*)d_out;

  // workspace carve (bf16): total 100,663,296 el = 192 MiB
  bf16* xb  = (bf16*)d_ws;                 // B*S*D
  bf16* wqb = xb + (size_t)BB * SS * DD;   // D*D each
  bf16* wkb = wqb + (size_t)DD * DD;
  bf16* wvb = wkb + (size_t)DD * DD;
  bf16* wob = wvb + (size_t)DD * DD;
  bf16* Qb  = wob + (size_t)DD * DD;       // (B,H,S,128)
  bf16* Kbf = Qb + (size_t)BB * SS * DD;
  bf16* Vtb = Kbf + (size_t)BB * SS * DD;  // (B,H,128,S)
  bf16* Ob  = Vtb + (size_t)BB * SS * DD;  // (B,S,2048)

  const int nx = BB * SS * DD;
  const int nw = DD * DD;
  cast_kernel<<<nx / 4 / 256, 256, 0, stream>>>(x, xb, nx / 4);
  cast_kernel<<<nw / 4 / 256, 256, 0, stream>>>(wq, wqb, nw / 4);
  cast_kernel<<<nw / 4 / 256, 256, 0, stream>>>(wk, wkb, nw / 4);
  cast_kernel<<<nw / 4 / 256, 256, 0, stream>>>(wv, wvb, nw / 4);
  cast_kernel<<<nw / 4 / 256, 256, 0, stream>>>(wo, wob, nw / 4);

  dim3 gg(DD / 128, (BB * SS) / 128);  // (16, 64)
  gemm_bt<0><<<gg, 256, 0, stream>>>(xb, wqb, Qb, nullptr, BB * SS, DD, DD);
  gemm_bt<0><<<gg, 256, 0, stream>>>(xb, wkb, Kbf, nullptr, BB * SS, DD, DD);
  gemm_bt<1><<<gg, 256, 0, stream>>>(xb, wvb, Vtb, nullptr, BB * SS, DD, DD);

  const int nrope = BB * HH * SS * 64;
  rope_kernel<<<nrope / 256, 256, 0, stream>>>(Qb, Kbf, pos, nrope);

  flash_attn<<<dim3(SS / 64, BB * HH), 256, 0, stream>>>(Qb, Kbf, Vtb, Ob);

  gemm_bt<2><<<gg, 256, 0, stream>>>(Ob, wob, nullptr, out, BB * SS, DD, DD);
}

// Round 4
// 812.374 us; speedup vs baseline: 1.4056x; 1.0254x over previous
//
#include <hip/hip_runtime.h>
#include <math.h>

typedef __bf16 bf16;
typedef bf16 bf16x8 __attribute__((ext_vector_type(8)));
typedef bf16 bf16x4v __attribute__((ext_vector_type(4)));
typedef float f32x4 __attribute__((ext_vector_type(4)));

// Problem constants (B=4, S=2048, D=2048, H=16, dh=128)
#define BB 4
#define SS 2048
#define DD 2048
#define HH 16
#define DH 128

__device__ __forceinline__ void gload_lds16(const bf16* g, bf16* l) {
  __builtin_amdgcn_global_load_lds(
      (const __attribute__((address_space(1))) void*)g,
      (__attribute__((address_space(3))) void*)l, 16, 0, 0);
}

// ---------------------------------------------------------------- cast f32->bf16
__global__ __launch_bounds__(256) void cast_kernel(const float* __restrict__ in,
                                                   bf16* __restrict__ out, int n4) {
  int i = blockIdx.x * blockDim.x + threadIdx.x;
  if (i < n4) {
    const float4 v = ((const float4*)in)[i];
    bf16x4v o = {(bf16)v.x, (bf16)v.y, (bf16)v.z, (bf16)v.w};
    ((bf16x4v*)out)[i] = o;
  }
}

// cast all 4 weight matrices in one launch (each D*D, select by index)
__global__ __launch_bounds__(256) void cast4_kernel(const float* __restrict__ w0,
                                                    const float* __restrict__ w1,
                                                    const float* __restrict__ w2,
                                                    const float* __restrict__ w3,
                                                    bf16* __restrict__ out) {
  const int i = blockIdx.x * blockDim.x + threadIdx.x;  // float4 index over 4*D*D
  const int per = (DD * DD) / 4;
  const int sel = i / per, off = i - sel * per;
  const float* src = (sel == 0) ? w0 : (sel == 1) ? w1 : (sel == 2) ? w2 : w3;
  const float4 v = ((const float4*)src)[off];
  bf16x4v o = {(bf16)v.x, (bf16)v.y, (bf16)v.z, (bf16)v.w};
  ((bf16x4v*)(out + (size_t)sel * DD * DD))[off] = o;
}

// ---------------------------------------------------------------- GEMM  C[m,n] = sum_k A[m,k]*W[n,k]
// MODE 0: bf16 out scattered to (b,h,s,d)   [Q, K before RoPE]
// MODE 1: bf16 out scattered to (b,h,d,s)   [V transposed]
// MODE 2: fp32 out row-major (m,n)          [final projection]
template <int MODE>
__global__ __launch_bounds__(256) void gemm_bt(const bf16* __restrict__ A,
                                               const bf16* __restrict__ Bw,
                                               bf16* __restrict__ Cb,
                                               float* __restrict__ Cf,
                                               int M, int N, int K) {
  __shared__ alignas(16) bf16 lA[128 * 64];
  __shared__ alignas(16) bf16 lB[128 * 64];
  const int tid = threadIdx.x;
  const int wave = tid >> 6, lane = tid & 63;
  const int quad = lane >> 4, l15 = lane & 15;
  const int m0 = blockIdx.y * 128, n0 = blockIdx.x * 128;
  const int wm = (wave >> 1) * 64, wn = (wave & 1) * 64;

  f32x4 acc[4][4] = {};

  for (int k0 = 0; k0 < K; k0 += 64) {
    __syncthreads();
#pragma unroll
    for (int i = 0; i < 4; ++i) {
      const int p = (wave * 4 + i) * 64 + lane;  // 16B chunk id, 0..1023
      const int r = p >> 3, c = p & 7;           // tile row / chunk-in-row
      gload_lds16(A + (size_t)(m0 + r) * K + k0 + c * 8, lA + (size_t)(wave * 4 + i) * 512);
      gload_lds16(Bw + (size_t)(n0 + r) * K + k0 + c * 8, lB + (size_t)(wave * 4 + i) * 512);
    }
    __syncthreads();
#pragma unroll
    for (int kk = 0; kk < 2; ++kk) {
      bf16x8 af[4], bfr[4];
#pragma unroll
      for (int t = 0; t < 4; ++t)
        af[t] = *(const bf16x8*)(lA + (wm + t * 16 + l15) * 64 + kk * 32 + quad * 8);
#pragma unroll
      for (int t = 0; t < 4; ++t)
        bfr[t] = *(const bf16x8*)(lB + (wn + t * 16 + l15) * 64 + kk * 32 + quad * 8);
#pragma unroll
      for (int mt = 0; mt < 4; ++mt)
#pragma unroll
        for (int nt = 0; nt < 4; ++nt)
          acc[mt][nt] = __builtin_amdgcn_mfma_f32_16x16x32_bf16(af[mt], bfr[nt], acc[mt][nt], 0, 0, 0);
    }
  }

#pragma unroll
  for (int mt = 0; mt < 4; ++mt) {
#pragma unroll
    for (int nt = 0; nt < 4; ++nt) {
#pragma unroll
      for (int r = 0; r < 4; ++r) {
        const int row = m0 + wm + mt * 16 + quad * 4 + r;  // C/D layout: row=quad*4+reg
        const int col = n0 + wn + nt * 16 + l15;           //             col=lane&15
        const float v = acc[mt][nt][r];
        if (MODE == 0) {
          const int b = row >> 11, s = row & (SS - 1);
          const int h = col >> 7, d = col & (DH - 1);
          Cb[((((size_t)b * HH + h) * SS + s) << 7) + d] = (bf16)v;
        } else if (MODE == 1) {
          const int b = row >> 11, s = row & (SS - 1);
          const int h = col >> 7, d = col & (DH - 1);
          Cb[(((size_t)b * HH + h) * DH + d) * SS + s] = (bf16)v;
        } else {
          Cf[(size_t)row * N + col] = v;
        }
      }
    }
  }
}

// ---------------------------------------------------------------- RoPE in-place on Q,K (b,h,s,d) bf16
__global__ __launch_bounds__(256) void rope_kernel(bf16* __restrict__ Q, bf16* __restrict__ Kb,
                                                   const int* __restrict__ pos, int total) {
  int idx = blockIdx.x * blockDim.x + threadIdx.x;
  if (idx >= total) return;            // total = B*H*S*64
  const int i = idx & 63;              // pair index
  const int s = (idx >> 6) & (SS - 1);
  const int bh = idx >> 17;            // S*64 = 2^17
  const size_t base = (((size_t)bh * SS + s) << 7) + 2 * i;
  const float p = (float)pos[s];
  const float inv_freq = exp2f((float)i * (-2.0f / 128.0f) * 13.28771238f);  // log2(10000)
  const float ang = p * inv_freq;
  float sv, cv;
  sincosf(ang, &sv, &cv);
  {
    float x1 = (float)Q[base], x2 = (float)Q[base + 1];
    Q[base] = (bf16)(x1 * cv - x2 * sv);
    Q[base + 1] = (bf16)(x1 * sv + x2 * cv);
  }
  {
    float x1 = (float)Kb[base], x2 = (float)Kb[base + 1];
    Kb[base] = (bf16)(x1 * cv - x2 * sv);
    Kb[base + 1] = (bf16)(x1 * sv + x2 * cv);
  }
}

// ---------------------------------------------------------------- flash attention v4
// Key-split QK^T + d-split PV. K/V fragments DIRECT from global (register
// prefetch, no LDS staging). Only P round-trips LDS (double-buffered, XOR
// swizzled, 1 barrier/iter). Static-max softmax (scores bounded): no cross-lane
// ops in the loop, no accumulator rescale; per-lane l merged in epilogue.
// Q,K: (B,H,S,128) bf16 ; Vt: (B,H,128,S) bf16 ; O: (B,S,H*128) bf16
__global__ __launch_bounds__(256, 2) void flash_attn(const bf16* __restrict__ Q,
                                                     const bf16* __restrict__ Kg,
                                                     const bf16* __restrict__ Vt,
                                                     bf16* __restrict__ O) {
  __shared__ alignas(16) bf16 lP[2][64 * 64];  // [q][key], 16B-chunk XOR swizzle c^(q&7)
  __shared__ float lred[4 * 64];               // per-wave l partials

  const int tid = threadIdx.x;
  const int wave = tid >> 6, lane = tid & 63;
  const int quad = lane >> 4, l15 = lane & 15;
  const int bh = blockIdx.y;
  const int q0 = (gridDim.x - 1 - blockIdx.x) * 64;  // heavy blocks first
  const bf16* Qh = Q + (size_t)bh * SS * DH;
  const bf16* Kh = Kg + (size_t)bh * SS * DH;
  const bf16* Vh = Vt + (size_t)bh * DH * SS;

  // Q fragments: B-operand for all 64 q (loop-invariant).
  // qf[qt][t] = Q[q0+qt*16+l15][t*32+quad*8 .. +8]
  bf16x8 qf[4][4];
#pragma unroll
  for (int qt = 0; qt < 4; ++qt)
#pragma unroll
    for (int t = 0; t < 4; ++t)
      qf[qt][t] = *(const bf16x8*)(Qh + (size_t)(q0 + qt * 16 + l15) * DH + t * 32 + quad * 8);

  // K fragment base: wave owns keys [kb*64 + wave*16, +16); A-operand rows = l15.
  const bf16* Kbase = Kh + (size_t)(wave * 16 + l15) * DH + quad * 8;
  // V fragment base: wave owns d in [wave*32, +32); B[k][d]: lane reads V^T[d][8 keys].
  const bf16* Vbase = Vh + (size_t)(wave * 32 + l15) * SS + quad * 8;

  const int nkb = (q0 >> 6) + 1;
  const float cs = 0.12751649736f;  // log2(e)/sqrt(128)
  const float MSTAT = 20.0f;        // static max (log2 domain); |s*cs| <= ~19 worst-case

  bf16x8 kf[4], kn[4], vf[4];
#pragma unroll
  for (int t = 0; t < 4; ++t) kf[t] = *(const bf16x8*)(Kbase + t * 32);

  float lsum[4] = {0.f, 0.f, 0.f, 0.f};
  f32x4 oacc[4][2] = {};

  for (int kb = 0; kb < nkb; ++kb) {
    // prefetch next K tile; load this tile's V fragments (used after barrier)
    if (kb + 1 < nkb) {
#pragma unroll
      for (int t = 0; t < 4; ++t)
        kn[t] = *(const bf16x8*)(Kbase + (size_t)(kb + 1) * 64 * DH + t * 32);
    }
#pragma unroll
    for (int kk = 0; kk < 2; ++kk)
#pragma unroll
      for (int nd = 0; nd < 2; ++nd)
        vf[kk * 2 + nd] = *(const bf16x8*)(Vbase + (size_t)(nd * 16) * SS + kb * 64 + kk * 32);

    // S^T[key_local, q]: A = kf (m=key), B = qf (n=q); 16 MFMAs
    f32x4 sacc[4] = {};
#pragma unroll
    for (int t = 0; t < 4; ++t)
#pragma unroll
      for (int qt = 0; qt < 4; ++qt)
        sacc[qt] = __builtin_amdgcn_mfma_f32_16x16x32_bf16(kf[t], qf[qt][t], sacc[qt], 0, 0, 0);

    // static-max softmax + P write (C-layout rows = keys quad*4+r, col q = l15)
    bf16* lPb = lP[kb & 1];
    const int cw = wave * 2 + (quad >> 1);  // 16B chunk of this lane's b64 write
#pragma unroll
    for (int qt = 0; qt < 4; ++qt) {
      const int qglob = q0 + qt * 16 + l15;
      bf16x4v pk;
      float ls = 0.f;
#pragma unroll
      for (int r = 0; r < 4; ++r) {
        const int key = kb * 64 + wave * 16 + quad * 4 + r;
        const float e = (key <= qglob) ? exp2f(fmaf(sacc[qt][r], cs, -MSTAT)) : 0.f;
        ls += e;
        pk[r] = (bf16)e;
      }
      lsum[qt] += ls;
      const int row = qt * 16 + l15;
      *(bf16x4v*)(lPb + row * 64 + (cw ^ (l15 & 7)) * 8 + (quad & 1) * 4) = pk;
    }
    __syncthreads();  // P visible; prev buffer free for next iter

    // PV: O[q, d] += P[q, key] * V[key, d]; A = P (LDS), B = vf; 16 MFMAs
#pragma unroll
    for (int mt = 0; mt < 4; ++mt) {
#pragma unroll
      for (int kk = 0; kk < 2; ++kk) {
        const int cc = (kk * 4 + quad) ^ (l15 & 7);
        bf16x8 ap = *(const bf16x8*)(lPb + (mt * 16 + l15) * 64 + cc * 8);
        oacc[mt][0] = __builtin_amdgcn_mfma_f32_16x16x32_bf16(ap, vf[kk * 2 + 0], oacc[mt][0], 0, 0, 0);
        oacc[mt][1] = __builtin_amdgcn_mfma_f32_16x16x32_bf16(ap, vf[kk * 2 + 1], oacc[mt][1], 0, 0, 0);
      }
    }
#pragma unroll
    for (int t = 0; t < 4; ++t) kf[t] = kn[t];
  }

  // ---- epilogue: merge l across quads (shfl) and waves (LDS), write O/l ----
#pragma unroll
  for (int qt = 0; qt < 4; ++qt) {
    lsum[qt] += __shfl_xor(lsum[qt], 16);
    lsum[qt] += __shfl_xor(lsum[qt], 32);
  }
  if (quad == 0) {
#pragma unroll
    for (int qt = 0; qt < 4; ++qt) lred[wave * 64 + qt * 16 + l15] = lsum[qt];
  }
  __syncthreads();

  const int b = bh >> 4, h = bh & 15;
#pragma unroll
  for (int mt = 0; mt < 4; ++mt) {
#pragma unroll
    for (int r = 0; r < 4; ++r) {
      const int qrow = mt * 16 + quad * 4 + r;
      const float lt = lred[qrow] + lred[64 + qrow] + lred[128 + qrow] + lred[192 + qrow];
      const float il = 1.0f / lt;
      bf16* orow = O + ((size_t)b * SS + q0 + qrow) * DD + h * DH + wave * 32;
      orow[l15] = (bf16)(oacc[mt][0][r] * il);
      orow[16 + l15] = (bf16)(oacc[mt][1][r] * il);
    }
  }
}

// ---------------------------------------------------------------- launch
extern "C" void kernel_launch(void* const* d_in, const int* in_sizes, int n_in,
                              void* d_out, int out_size, void* d_ws, size_t ws_size,
                              hipStream_t stream) {
  (void)in_sizes; (void)n_in; (void)out_size; (void)ws_size;
  const float* x = (const float*)d_in[0];
  const int* pos = (const int*)d_in[1];
  const float* wq = (const float*)d_in[2];
  const float* wk = (const float*)d_in[3];
  const float* wv = (const float*)d_in[4];
  const float* wo = (const float*)d_in[5];
  float* out = (float*)d_out;

  // workspace carve (bf16): total 100,663,296 el = 192 MiB
  bf16* xb  = (bf16*)d_ws;                 // B*S*D
  bf16* wqb = xb + (size_t)BB * SS * DD;   // D*D each (wq,wk,wv,wo contiguous)
  bf16* wkb = wqb + (size_t)DD * DD;
  bf16* wvb = wkb + (size_t)DD * DD;
  bf16* wob = wvb + (size_t)DD * DD;
  bf16* Qb  = wob + (size_t)DD * DD;       // (B,H,S,128)
  bf16* Kbf = Qb + (size_t)BB * SS * DD;
  bf16* Vtb = Kbf + (size_t)BB * SS * DD;  // (B,H,128,S)
  bf16* Ob  = Vtb + (size_t)BB * SS * DD;  // (B,S,2048)

  const int nx = BB * SS * DD;
  cast_kernel<<<nx / 4 / 256, 256, 0, stream>>>(x, xb, nx / 4);
  cast4_kernel<<<4 * DD * DD / 4 / 256, 256, 0, stream>>>(wq, wk, wv, wo, wqb);

  dim3 gg(DD / 128, (BB * SS) / 128);  // (16, 64)
  gemm_bt<0><<<gg, 256, 0, stream>>>(xb, wqb, Qb, nullptr, BB * SS, DD, DD);
  gemm_bt<0><<<gg, 256, 0, stream>>>(xb, wkb, Kbf, nullptr, BB * SS, DD, DD);
  gemm_bt<1><<<gg, 256, 0, stream>>>(xb, wvb, Vtb, nullptr, BB * SS, DD, DD);

  const int nrope = BB * HH * SS * 64;
  rope_kernel<<<nrope / 256, 256, 0, stream>>>(Qb, Kbf, pos, nrope);

  flash_attn<<<dim3(SS / 64, BB * HH), 256, 0, stream>>>(Qb, Kbf, Vtb, Ob);

  gemm_bt<2><<<gg, 256, 0, stream>>>(Ob, wob, nullptr, out, BB * SS, DD, DD);
}

// Round 5
// 800.536 us; speedup vs baseline: 1.4263x; 1.0148x over previous
//
#include <hip/hip_runtime.h>
#include <math.h>

typedef __bf16 bf16;
typedef bf16 bf16x8 __attribute__((ext_vector_type(8)));
typedef bf16 bf16x4v __attribute__((ext_vector_type(4)));
typedef float f32x4 __attribute__((ext_vector_type(4)));

// Problem constants (B=4, S=2048, D=2048, H=16, dh=128)
#define BB 4
#define SS 2048
#define DD 2048
#define HH 16
#define DH 128

__device__ __forceinline__ void gload_lds16(const bf16* g, bf16* l) {
  __builtin_amdgcn_global_load_lds(
      (const __attribute__((address_space(1))) void*)g,
      (__attribute__((address_space(3))) void*)l, 16, 0, 0);
}

// ---------------------------------------------------------------- cast f32->bf16
__global__ __launch_bounds__(256) void cast_kernel(const float* __restrict__ in,
                                                   bf16* __restrict__ out, int n4) {
  int i = blockIdx.x * blockDim.x + threadIdx.x;
  if (i < n4) {
    const float4 v = ((const float4*)in)[i];
    bf16x4v o = {(bf16)v.x, (bf16)v.y, (bf16)v.z, (bf16)v.w};
    ((bf16x4v*)out)[i] = o;
  }
}

// cast all 4 weight matrices in one launch (each D*D, select by index)
__global__ __launch_bounds__(256) void cast4_kernel(const float* __restrict__ w0,
                                                    const float* __restrict__ w1,
                                                    const float* __restrict__ w2,
                                                    const float* __restrict__ w3,
                                                    bf16* __restrict__ out) {
  const int i = blockIdx.x * blockDim.x + threadIdx.x;  // float4 index over 4*D*D
  const int per = (DD * DD) / 4;
  const int sel = i / per, off = i - sel * per;
  const float* src = (sel == 0) ? w0 : (sel == 1) ? w1 : (sel == 2) ? w2 : w3;
  const float4 v = ((const float4*)src)[off];
  bf16x4v o = {(bf16)v.x, (bf16)v.y, (bf16)v.z, (bf16)v.w};
  ((bf16x4v*)(out + (size_t)sel * DD * DD))[off] = o;
}

// ---------------------------------------------------------------- GEMM  C[m,n] = sum_k A[m,k]*W[n,k]
// MODE 0: bf16 out + FUSED RoPE, scattered to (b,h,s,d)  [Q, K]
// MODE 1: bf16 out scattered to (b,h,d,s)                [V transposed]
// MODE 2: fp32 out row-major (m,n)                       [final projection]
template <int MODE>
__global__ __launch_bounds__(256) void gemm_bt(const bf16* __restrict__ A,
                                               const bf16* __restrict__ Bw,
                                               bf16* __restrict__ Cb,
                                               float* __restrict__ Cf,
                                               const int* __restrict__ pos,
                                               int M, int N, int K) {
  __shared__ alignas(16) bf16 lA[128 * 64];
  __shared__ alignas(16) bf16 lB[128 * 64];
  const int tid = threadIdx.x;
  const int wave = tid >> 6, lane = tid & 63;
  const int quad = lane >> 4, l15 = lane & 15;
  const int m0 = blockIdx.y * 128, n0 = blockIdx.x * 128;
  const int wm = (wave >> 1) * 64, wn = (wave & 1) * 64;

  f32x4 acc[4][4] = {};

  for (int k0 = 0; k0 < K; k0 += 64) {
    __syncthreads();
#pragma unroll
    for (int i = 0; i < 4; ++i) {
      const int p = (wave * 4 + i) * 64 + lane;  // 16B chunk id, 0..1023
      const int r = p >> 3, c = p & 7;           // tile row / chunk-in-row
      gload_lds16(A + (size_t)(m0 + r) * K + k0 + c * 8, lA + (size_t)(wave * 4 + i) * 512);
      gload_lds16(Bw + (size_t)(n0 + r) * K + k0 + c * 8, lB + (size_t)(wave * 4 + i) * 512);
    }
    __syncthreads();
#pragma unroll
    for (int kk = 0; kk < 2; ++kk) {
      bf16x8 af[4], bfr[4];
#pragma unroll
      for (int t = 0; t < 4; ++t)
        af[t] = *(const bf16x8*)(lA + (wm + t * 16 + l15) * 64 + kk * 32 + quad * 8);
#pragma unroll
      for (int t = 0; t < 4; ++t)
        bfr[t] = *(const bf16x8*)(lB + (wn + t * 16 + l15) * 64 + kk * 32 + quad * 8);
#pragma unroll
      for (int mt = 0; mt < 4; ++mt)
#pragma unroll
        for (int nt = 0; nt < 4; ++nt)
          acc[mt][nt] = __builtin_amdgcn_mfma_f32_16x16x32_bf16(af[mt], bfr[nt], acc[mt][nt], 0, 0, 0);
    }
  }

  float ps[4][4];
  if (MODE == 0) {
#pragma unroll
    for (int mt = 0; mt < 4; ++mt)
#pragma unroll
      for (int r = 0; r < 4; ++r)
        ps[mt][r] = (float)pos[(m0 + wm + mt * 16 + quad * 4 + r) & (SS - 1)];
  }

#pragma unroll
  for (int nt = 0; nt < 4; ++nt) {
    const int col = n0 + wn + nt * 16 + l15;
    float invf = 0.f, sgn = 0.f;
    if (MODE == 0) {
      const int d = col & (DH - 1);
      invf = exp2f((float)(d >> 1) * (-13.28771238f / 64.0f));  // 10000^(-2i/128)
      sgn = (d & 1) ? 1.0f : -1.0f;
    }
#pragma unroll
    for (int mt = 0; mt < 4; ++mt) {
#pragma unroll
      for (int r = 0; r < 4; ++r) {
        const int row = m0 + wm + mt * 16 + quad * 4 + r;  // C/D layout: row=quad*4+reg
        float v = acc[mt][nt][r];
        if (MODE == 0) {
          // fused RoPE: pair partner is adjacent lane (col differs by 1, same row)
          const float partner = __shfl_xor(v, 1);
          float sn, cn;
          __sincosf(ps[mt][r] * invf, &sn, &cn);
          v = fmaf(partner, sgn * sn, v * cn);
          const int b = row >> 11, s = row & (SS - 1);
          const int h = col >> 7, d = col & (DH - 1);
          Cb[((((size_t)b * HH + h) * SS + s) << 7) + d] = (bf16)v;
        } else if (MODE == 1) {
          const int b = row >> 11, s = row & (SS - 1);
          const int h = col >> 7, d = col & (DH - 1);
          Cb[(((size_t)b * HH + h) * DH + d) * SS + s] = (bf16)v;
        } else {
          Cf[(size_t)row * N + col] = v;
        }
      }
    }
  }
}

// ---------------------------------------------------------------- flash attention v5 (software-pipelined)
// Key-split QK^T + d-split PV; K/V direct from global (reg prefetch: K dist-2,
// V dist-1); only P through LDS (double-buffered, XOR-swizzled, 1 barrier/iter).
// Pipeline: at iter k issue QK(k+1) MFMAs, then PV(k) MFMAs (independent),
// then softmax(k+1) VALU under the MFMA shadow. Static-max softmax.
// Q,K: (B,H,S,128) bf16 ; Vt: (B,H,128,S) bf16 ; O: (B,S,H*128) bf16
__global__ __launch_bounds__(256, 2) void flash_attn(const bf16* __restrict__ Q,
                                                     const bf16* __restrict__ Kg,
                                                     const bf16* __restrict__ Vt,
                                                     bf16* __restrict__ O) {
  __shared__ alignas(16) bf16 lP[2][64 * 64];  // [q][key], 16B-chunk XOR swizzle
  __shared__ float lred[4 * 64];               // per-wave l partials

  const int tid = threadIdx.x;
  const int wave = tid >> 6, lane = tid & 63;
  const int quad = lane >> 4, l15 = lane & 15;
  const int bh = blockIdx.y;
  const int q0 = (gridDim.x - 1 - blockIdx.x) * 64;  // heavy blocks first
  const bf16* Qh = Q + (size_t)bh * SS * DH;
  const bf16* Kh = Kg + (size_t)bh * SS * DH;
  const bf16* Vh = Vt + (size_t)bh * DH * SS;

  // Q fragments: B-operand for all 64 q (loop-invariant)
  bf16x8 qf[4][4];
#pragma unroll
  for (int qt = 0; qt < 4; ++qt)
#pragma unroll
    for (int t = 0; t < 4; ++t)
      qf[qt][t] = *(const bf16x8*)(Qh + (size_t)(q0 + qt * 16 + l15) * DH + t * 32 + quad * 8);

  const bf16* Kbase = Kh + (size_t)(wave * 16 + l15) * DH + quad * 8;  // A-rows = keys
  const bf16* Vbase = Vh + (size_t)(wave * 32 + l15) * SS + quad * 8;  // B-rows = d

  const int nkb = (q0 >> 6) + 1;
  const float cs = 0.12751649736f;  // log2(e)/sqrt(128)
  const float MSTAT = 20.0f;        // static max (log2 domain)

  float lsum[4] = {0.f, 0.f, 0.f, 0.f};
  f32x4 oacc[4][2] = {};
  f32x4 sacc[4];

  bf16x8 kf[4], kn[4], vf[4], vn[4];
#pragma unroll
  for (int t = 0; t < 4; ++t) kf[t] = *(const bf16x8*)(Kbase + t * 32);  // K(0)
#pragma unroll
  for (int kk = 0; kk < 2; ++kk)
#pragma unroll
    for (int nd = 0; nd < 2; ++nd)
      vf[kk * 2 + nd] = *(const bf16x8*)(Vbase + (size_t)(nd * 16) * SS + kk * 32);  // V(0)
#pragma unroll
  for (int t = 0; t < 4; ++t)
    kn[t] = (nkb > 1) ? *(const bf16x8*)(Kbase + (size_t)64 * DH + t * 32) : kf[t];  // K(1)

  auto softmax_write = [&](int kbn) {
    bf16* lPb = lP[kbn & 1];
    const int cw = wave * 2 + (quad >> 1);
#pragma unroll
    for (int qt = 0; qt < 4; ++qt) {
      const int qglob = q0 + qt * 16 + l15;
      bf16x4v pk;
      float ls = 0.f;
#pragma unroll
      for (int r = 0; r < 4; ++r) {
        const int key = kbn * 64 + wave * 16 + quad * 4 + r;
        const float e = (key <= qglob) ? exp2f(fmaf(sacc[qt][r], cs, -MSTAT)) : 0.f;
        ls += e;
        pk[r] = (bf16)e;
      }
      lsum[qt] += ls;
      *(bf16x4v*)(lPb + (qt * 16 + l15) * 64 + (cw ^ (l15 & 7)) * 8 + (quad & 1) * 4) = pk;
    }
  };

  // prologue: QK(0), softmax(0), P(0) -> buffer 0
#pragma unroll
  for (int qt = 0; qt < 4; ++qt) sacc[qt] = (f32x4){0.f, 0.f, 0.f, 0.f};
#pragma unroll
  for (int t = 0; t < 4; ++t)
#pragma unroll
    for (int qt = 0; qt < 4; ++qt)
      sacc[qt] = __builtin_amdgcn_mfma_f32_16x16x32_bf16(kf[t], qf[qt][t], sacc[qt], 0, 0, 0);
  softmax_write(0);
#pragma unroll
  for (int t = 0; t < 4; ++t) kf[t] = kn[t];  // kf = K(1)

  for (int kb = 0; kb < nkb; ++kb) {
    __syncthreads();  // P(kb) visible
    const bool more = (kb + 1 < nkb);
    if (kb + 2 < nkb) {
#pragma unroll
      for (int t = 0; t < 4; ++t)
        kn[t] = *(const bf16x8*)(Kbase + (size_t)(kb + 2) * 64 * DH + t * 32);
    }
    if (more) {
#pragma unroll
      for (int kk = 0; kk < 2; ++kk)
#pragma unroll
        for (int nd = 0; nd < 2; ++nd)
          vn[kk * 2 + nd] = *(const bf16x8*)(Vbase + (size_t)(nd * 16) * SS + (kb + 1) * 64 + kk * 32);
      // QK(kb+1) with kf
#pragma unroll
      for (int qt = 0; qt < 4; ++qt) sacc[qt] = (f32x4){0.f, 0.f, 0.f, 0.f};
#pragma unroll
      for (int t = 0; t < 4; ++t)
#pragma unroll
        for (int qt = 0; qt < 4; ++qt)
          sacc[qt] = __builtin_amdgcn_mfma_f32_16x16x32_bf16(kf[t], qf[qt][t], sacc[qt], 0, 0, 0);
    }

    // PV(kb): reads P from lP[kb&1] + vf regs
    const bf16* lPb = lP[kb & 1];
#pragma unroll
    for (int mt = 0; mt < 4; ++mt) {
#pragma unroll
      for (int kk = 0; kk < 2; ++kk) {
        const int cc = (kk * 4 + quad) ^ (l15 & 7);
        bf16x8 ap = *(const bf16x8*)(lPb + (mt * 16 + l15) * 64 + cc * 8);
        oacc[mt][0] = __builtin_amdgcn_mfma_f32_16x16x32_bf16(ap, vf[kk * 2 + 0], oacc[mt][0], 0, 0, 0);
        oacc[mt][1] = __builtin_amdgcn_mfma_f32_16x16x32_bf16(ap, vf[kk * 2 + 1], oacc[mt][1], 0, 0, 0);
      }
    }

    if (more) softmax_write(kb + 1);  // under PV MFMA shadow; other buffer
#pragma unroll
    for (int t = 0; t < 4; ++t) kf[t] = kn[t];
#pragma unroll
    for (int i = 0; i < 4; ++i) vf[i] = vn[i];
  }

  // ---- epilogue: merge l across quads (shfl) and waves (LDS) ----
#pragma unroll
  for (int qt = 0; qt < 4; ++qt) {
    lsum[qt] += __shfl_xor(lsum[qt], 16);
    lsum[qt] += __shfl_xor(lsum[qt], 32);
  }
  if (quad == 0) {
#pragma unroll
    for (int qt = 0; qt < 4; ++qt) lred[wave * 64 + qt * 16 + l15] = lsum[qt];
  }
  __syncthreads();

  const int b = bh >> 4, h = bh & 15;
#pragma unroll
  for (int mt = 0; mt < 4; ++mt) {
#pragma unroll
    for (int r = 0; r < 4; ++r) {
      const int qrow = mt * 16 + quad * 4 + r;
      const float lt = lred[qrow] + lred[64 + qrow] + lred[128 + qrow] + lred[192 + qrow];
      const float il = 1.0f / lt;
      bf16* orow = O + ((size_t)b * SS + q0 + qrow) * DD + h * DH + wave * 32;
      orow[l15] = (bf16)(oacc[mt][0][r] * il);
      orow[16 + l15] = (bf16)(oacc[mt][1][r] * il);
    }
  }
}

// ---------------------------------------------------------------- launch
extern "C" void kernel_launch(void* const* d_in, const int* in_sizes, int n_in,
                              void* d_out, int out_size, void* d_ws, size_t ws_size,
                              hipStream_t stream) {
  (void)in_sizes; (void)n_in; (void)out_size; (void)ws_size;
  const float* x = (const float*)d_in[0];
  const int* pos = (const int*)d_in[1];
  const float* wq = (const float*)d_in[2];
  const float* wk = (const float*)d_in[3];
  const float* wv = (const float*)d_in[4];
  const float* wo = (const float*)d_in[5];
  float* out = (float*)d_out;

  // workspace carve (bf16)
  bf16* xb  = (bf16*)d_ws;                 // B*S*D
  bf16* wqb = xb + (size_t)BB * SS * DD;   // D*D each (wq,wk,wv,wo contiguous)
  bf16* wkb = wqb + (size_t)DD * DD;
  bf16* wvb = wkb + (size_t)DD * DD;
  bf16* wob = wvb + (size_t)DD * DD;
  bf16* Qb  = wob + (size_t)DD * DD;       // (B,H,S,128)
  bf16* Kbf = Qb + (size_t)BB * SS * DD;
  bf16* Vtb = Kbf + (size_t)BB * SS * DD;  // (B,H,128,S)
  bf16* Ob  = Vtb + (size_t)BB * SS * DD;  // (B,S,2048)

  const int nx = BB * SS * DD;
  cast_kernel<<<nx / 4 / 256, 256, 0, stream>>>(x, xb, nx / 4);
  cast4_kernel<<<DD * DD / 256, 256, 0, stream>>>(wq, wk, wv, wo, wqb);

  dim3 gg(DD / 128, (BB * SS) / 128);  // (16, 64)
  gemm_bt<0><<<gg, 256, 0, stream>>>(xb, wqb, Qb, nullptr, pos, BB * SS, DD, DD);
  gemm_bt<0><<<gg, 256, 0, stream>>>(xb, wkb, Kbf, nullptr, pos, BB * SS, DD, DD);
  gemm_bt<1><<<gg, 256, 0, stream>>>(xb, wvb, Vtb, nullptr, nullptr, BB * SS, DD, DD);

  flash_attn<<<dim3(SS / 64, BB * HH), 256, 0, stream>>>(Qb, Kbf, Vtb, Ob);

  gemm_bt<2><<<gg, 256, 0, stream>>>(Ob, wob, nullptr, out, nullptr, BB * SS, DD, DD);
}